// Round 6
// baseline (759.781 us; speedup 1.0000x reference)
//
#include <hip/hip_runtime.h>
#include <cmath>

// Problem constants (fixed by the reference).
#define Bn    16384
#define Tn    2048
#define HIDn  5
#define NBINS 2048

typedef float v2f __attribute__((ext_vector_type(2)));

static __device__ __forceinline__ float rcp_fast(float v) {
    return __builtin_amdgcn_rcpf(v);
}
static __device__ __forceinline__ float exp2_fast(float v) {
    return __builtin_amdgcn_exp2f(v);
}
static __device__ __forceinline__ float med3(float x, float lo, float hi) {
    return __builtin_amdgcn_fmed3f(x, lo, hi);   // 1-op clamp
}

// Broadcast lane (8g + K) to all lanes of each 8-lane group (ds_swizzle BitMode:
// new_src = (lane & 0x18) | K).
template <int K>
static __device__ __forceinline__ float bcast8(float v) {
    return __int_as_float(
        __builtin_amdgcn_ds_swizzle(__float_as_int(v), (K << 5) | 0x18));
}

// Host-generated activation polynomial coefficients (see kernel_launch):
// base G(y) ~ tanh(4*sqrt(y))/(4*sqrt(y)) on y in [0,1], Chebyshev interp.
//   sig[14]   = 2*G  : sigma(p) = 0.5 + w*Psig(w^2),  w = p/8 (clamped +-1)
//   gg[10]    = G    : tanh(g)/4 = wg*Pg(wg^2),       wg = g/4 (clamped +-1)
//   spine[14] = 4*G  : tanh(c)  = c4*Ps(c4^2),        c4 = c/4 (clamped +-1)
struct ActCoeffs {
    float sig[14];
    float gg[10];
    float spine[14];
};

// Estrin evaluation, scalar. N in {10, 14}; depth-5 dependency tree.
template <int N>
static __device__ __forceinline__ float poly_eval(const float* C, float z) {
    const float z2 = z * z, z4 = z2 * z2, z8 = z4 * z4;
    if constexpr (N == 14) {
        const float A0 = fmaf(z, C[1],  C[0]),  A1 = fmaf(z, C[3],  C[2]);
        const float A2 = fmaf(z, C[5],  C[4]),  A3 = fmaf(z, C[7],  C[6]);
        const float A4 = fmaf(z, C[9],  C[8]),  A5 = fmaf(z, C[11], C[10]);
        const float A6 = fmaf(z, C[13], C[12]);
        const float B0 = fmaf(z2, A1, A0), B1 = fmaf(z2, A3, A2), B2 = fmaf(z2, A5, A4);
        const float D0 = fmaf(z4, B1, B0), D1 = fmaf(z4, A6, B2);
        return fmaf(z8, D1, D0);
    } else {
        const float A0 = fmaf(z, C[1], C[0]),  A1 = fmaf(z, C[3], C[2]);
        const float A2 = fmaf(z, C[5], C[4]),  A3 = fmaf(z, C[7], C[6]);
        const float A4 = fmaf(z, C[9], C[8]);
        const float B0 = fmaf(z2, A1, A0), B1 = fmaf(z2, A3, A2);
        const float D0 = fmaf(z4, B1, B0);
        return fmaf(z8, A4, D0);
    }
}

// Estrin evaluation, packed pair (same coefficients on both halves).
static __device__ __forceinline__ v2f poly_eval2_14(const float* C, v2f z) {
    const v2f z2 = z * z, z4 = z2 * z2, z8 = z4 * z4;
    const v2f A0 = z * C[1]  + C[0],  A1 = z * C[3]  + C[2];
    const v2f A2 = z * C[5]  + C[4],  A3 = z * C[7]  + C[6];
    const v2f A4 = z * C[9]  + C[8],  A5 = z * C[11] + C[10];
    const v2f A6 = z * C[13] + C[12];
    const v2f B0 = z2 * A1 + A0, B1 = z2 * A3 + A2, B2 = z2 * A5 + A4;
    const v2f D0 = z4 * B1 + B0, D1 = z4 * A6 + B2;
    return z8 * D1 + D0;
}

// ---------------------------------------------------------------------------
// Pass 0: zero the global histogram bins (ws is poisoned 0xAA by the harness).
// ---------------------------------------------------------------------------
__global__ void zero_kernel(int* __restrict__ gbins) {
    gbins[blockIdx.x * 256 + threadIdx.x] = 0;
}

// ---------------------------------------------------------------------------
// Pass 1: lengths[b] = count of nonzero x[b,t] (exact reference mask.sum
// semantics) + histogram of descending-key d = NBINS - len.
// ---------------------------------------------------------------------------
__global__ __launch_bounds__(256) void len_kernel(const float* __restrict__ x,
                                                  int* __restrict__ lengths,
                                                  int* __restrict__ gbins) {
    const int gtid = blockIdx.x * 256 + threadIdx.x;
    const int row  = gtid >> 6;
    const int lane = threadIdx.x & 63;
    const float4* r = reinterpret_cast<const float4*>(x + (size_t)row * Tn);
    int cnt = 0;
    #pragma unroll
    for (int i = 0; i < Tn / 4 / 64; ++i) {
        float4 v = r[i * 64 + lane];
        cnt += (v.x != 0.0f) + (v.y != 0.0f) + (v.z != 0.0f) + (v.w != 0.0f);
    }
    #pragma unroll
    for (int off = 32; off > 0; off >>= 1) cnt += __shfl_xor(cnt, off, 64);
    if (lane == 0) {
        lengths[row] = cnt;
        const int d = max(0, min(NBINS - 1, NBINS - cnt));
        atomicAdd(&gbins[d], 1);
    }
}

// ---------------------------------------------------------------------------
// Pass 1.5: scan the histogram + scatter -> perm[] sorted by length DESC.
// ---------------------------------------------------------------------------
__global__ __launch_bounds__(1024) void sort_kernel(const int* __restrict__ lengths,
                                                    const int* __restrict__ gbins,
                                                    int* __restrict__ perm) {
    __shared__ int bins[NBINS];
    __shared__ int bsum[1024];
    const int tid = threadIdx.x;
    bins[tid]        = gbins[tid];
    bins[tid + 1024] = gbins[tid + 1024];
    __syncthreads();
    const int a0 = bins[2 * tid], a1 = bins[2 * tid + 1];
    const int s = a0 + a1;
    bsum[tid] = s;
    __syncthreads();
    int acc = s;
    for (int off = 1; off < 1024; off <<= 1) {
        int v = (tid >= off) ? bsum[tid - off] : 0;
        __syncthreads();
        acc += v;
        bsum[tid] = acc;
        __syncthreads();
    }
    const int excl = acc - s;
    bins[2 * tid]     = excl;
    bins[2 * tid + 1] = excl + a0;
    __syncthreads();
    for (int i = tid; i < Bn; i += 1024) {
        int d = NBINS - lengths[i];
        d = max(0, min(NBINS - 1, d));
        const int p = atomicAdd(&bins[d], 1);
        perm[p] = i;
    }
}

// ---------------------------------------------------------------------------
// Pass 2: LSTM. Structure = round-0 (8 lanes/group, lane k=min(lsub,4) owns
// hidden k, ds_swizzle broadcast, 2 waves/SIMD). Measured model: wall = 2048 x
// recurrence-cycle; cycle was bcast 120 + ladder 40 + gates(exp2->rcp 136) +
// cn 16 + spine(exp2->rcp 136) + commit 8 = 456. This round removes BOTH trans
// pairs from the cycle:
//   - activations via division-free Chebyshev polys (depth-5 Estrin, ~48cy
//     vs ~136cy trans chain), coefficients computed ON HOST vs libm tanh
//   - c-state kept in c/4 domain so all scales fold into host coefficients
//   - ladder as depth-3 tree (R4-verified)
//   - o-gate stays exp2+rcp (off the critical cycle)
// New cycle ~ 120 + 24 + 72 + 72 + 8 = 296cy.
// ---------------------------------------------------------------------------
__global__ __launch_bounds__(256, 2) void lstm_kernel(const float* __restrict__ x,
                                                      const float* __restrict__ Wih,
                                                      const float* __restrict__ Whh,
                                                      const float* __restrict__ bih,
                                                      const float* __restrict__ bhh,
                                                      const int* __restrict__ lengths,
                                                      const int* __restrict__ perm,
                                                      float* __restrict__ out,
                                                      ActCoeffs AC) {
    const int gtid = blockIdx.x * 256 + threadIdx.x;
    const int grp  = gtid >> 3;              // group-of-8 index = sorted rank
    const int lsub = threadIdx.x & 7;
    const int k    = min(lsub, 4);           // owned hidden index

    // Symmetry-break: co-resident blocks on a CU get different priority.
    if ((blockIdx.x >> 8) & 1) __builtin_amdgcn_s_setprio(1);

    const int b   = perm[grp];
    const int len = lengths[b];

    // Gate rows: i=k, f=5+k, g=10+k, o=15+k. Pair A=(i,f) scaled 1/8 (poly
    // sigma arg w=p/8), pair B=(g,o): g scaled 1/4 (poly tanh arg), o scaled
    // -log2e (exp2 sigmoid).
    const float SA = 0.125f;                 // 1/8 for i,f
    const float SG = 0.25f;                  // 1/4 for g
    const float SO = -1.4426950408889634f;   // -log2(e) for o
    v2f wihA, wihB, bA, bB, whhA[HIDn], whhB[HIDn];
    {
        const int gi = k, gf = 5 + k, gg = 10 + k, go = 15 + k;
        wihA = (v2f){ Wih[gi] * SA, Wih[gf] * SA };
        wihB = (v2f){ Wih[gg] * SG, Wih[go] * SO };
        bA   = (v2f){ (bih[gi] + bhh[gi]) * SA, (bih[gf] + bhh[gf]) * SA };
        bB   = (v2f){ (bih[gg] + bhh[gg]) * SG, (bih[go] + bhh[go]) * SO };
        #pragma unroll
        for (int kk = 0; kk < HIDn; ++kk) {
            whhA[kk] = (v2f){ Whh[gi * HIDn + kk] * SA, Whh[gf * HIDn + kk] * SA };
            whhB[kk] = (v2f){ Whh[gg * HIDn + kk] * SG, Whh[go * HIDn + kk] * SO };
        }
    }

    const float* xrow = x + (size_t)b * Tn;
    float h0 = 0, h1 = 0, h2 = 0, h3 = 0, h4 = 0;
    float hq = 0, c4 = 0;                    // c kept in c/4 domain

    float4 xq = *reinterpret_cast<const float4*>(xrow);
    for (int t = 0; __any(t < len); t += 4) {
        const float4 xn = *reinterpret_cast<const float4*>(xrow + min(t + 4, Tn - 4));
        const float xs[4] = { xq.x, xq.y, xq.z, xq.w };
        #pragma unroll
        for (int s = 0; s < 4; ++s) {
            const float xv = xs[s];
            // Pre-activations: x-part off-chain, depth-3 tree over h0..h4.
            const v2f xA = xv * wihA + bA;
            const v2f xB = xv * wihB + bB;
            const v2f tA0 = h0 * whhA[0] + xA;
            const v2f tB0 = h0 * whhB[0] + xB;
            const v2f mA2 = h2 * whhA[2];
            const v2f mB2 = h2 * whhB[2];
            const v2f tA1 = h1 * whhA[1] + mA2;
            const v2f tB1 = h1 * whhB[1] + mB2;
            const v2f mA4 = h4 * whhA[4];
            const v2f mB4 = h4 * whhB[4];
            const v2f tA2 = h3 * whhA[3] + mA4;
            const v2f tB2 = h3 * whhB[3] + mB4;
            const v2f pA = (tA0 + tA1) + tA2;    // (w_i, w_f) = (p_i, p_f)/8
            const v2f pB = (tB0 + tB1) + tB2;    // (w_g, e_o-arg)

            // sigma(i), sigma(f): packed poly. w clamped +-1 (p +- 8).
            v2f wA;
            wA.x = med3(pA.x, -1.0f, 1.0f);
            wA.y = med3(pA.y, -1.0f, 1.0f);
            const v2f zA = wA * wA;
            const v2f Ps = poly_eval2_14(AC.sig, zA);
            const v2f sAB = wA * Ps + 0.5f;      // (sigma_i, sigma_f)

            // tanh(g)/4: scalar poly, wg clamped +-1 (g +- 4).
            const float wg  = med3(pB.x, -1.0f, 1.0f);
            const float Pg  = poly_eval<10>(AC.gg, wg * wg);
            const float tg4 = wg * Pg;

            // sigma(o): exp2 path (off the critical cycle).
            const float eO = exp2_fast(pB.y);
            const float oo = rcp_fast(1.0f + eO);

            // c/4 update.
            const float cn4 = fmaf(sAB.y, c4, sAB.x * tg4);

            // Spine tanh(c) = c4*Ps(c4^2) (clamped copy; state unclamped).
            const float cc = med3(cn4, -1.0f, 1.0f);
            const float Pc = poly_eval<14>(AC.spine, cc * cc);
            const float ts = cc * Pc;
            const float hn = ts * oo;

            // Conditional commit (cndmask); frozen past len.
            const bool upd = (t + s) < len;
            c4 = upd ? cn4 : c4;
            hq = upd ? hn : hq;

            h0 = bcast8<0>(hq);
            h1 = bcast8<1>(hq);
            h2 = bcast8<2>(hq);
            h3 = bcast8<3>(hq);
            h4 = bcast8<4>(hq);
        }
        xq = xn;
    }

    if (lsub < HIDn) out[(size_t)b * HIDn + lsub] = hq;
}

// ---------------------------------------------------------------------------
// Host: Chebyshev interpolation of G(y) = tanh(4*sqrt(y))/(4*sqrt(y)) on
// y in [0,1] (Newton divided differences at Chebyshev nodes, double precision,
// expanded to monomials). G is analytic in y (tanh(x)/x is even in x).
// ---------------------------------------------------------------------------
static void tanh_base_poly(int N, double* c) {
    double yj[16], fj[16];
    for (int j = 0; j < N; ++j) {
        const double v = cos(M_PI * (2 * j + 1) / (2.0 * N));
        const double y = 0.5 + 0.5 * v;
        const double xx = 4.0 * sqrt(y);
        yj[j] = y;
        fj[j] = tanh(xx) / xx;
    }
    for (int k = 1; k < N; ++k)
        for (int j = N - 1; j >= k; --j)
            fj[j] = (fj[j] - fj[j - 1]) / (yj[j] - yj[j - k]);
    for (int i = 0; i < 16; ++i) c[i] = 0.0;
    c[0] = fj[N - 1];
    int deg = 0;
    for (int j = N - 2; j >= 0; --j) {
        for (int i = deg; i >= 0; --i) {
            c[i + 1] += c[i];
            c[i] = -yj[j] * c[i];
        }
        ++deg;
        c[0] += fj[j];
    }
}

extern "C" void kernel_launch(void* const* d_in, const int* in_sizes, int n_in,
                              void* d_out, int out_size, void* d_ws, size_t ws_size,
                              hipStream_t stream) {
    const float* x   = (const float*)d_in[0];  // [B,1,T,1]
    const float* Wih = (const float*)d_in[1];  // [20,1]
    const float* Whh = (const float*)d_in[2];  // [20,5]
    const float* bih = (const float*)d_in[3];  // [20]
    const float* bhh = (const float*)d_in[4];  // [20]
    float* out = (float*)d_out;                // [1,B,5]

    int* lengths = (int*)d_ws;                 // [0, Bn)
    int* perm    = lengths + Bn;               // [Bn, 2Bn)
    int* gbins   = perm + Bn;                  // [2Bn, 2Bn+NBINS)

    // Host-side coefficient generation (pure CPU, ~us).
    ActCoeffs AC;
    {
        double c14[16], c10[16];
        tanh_base_poly(14, c14);   // deg-13 in y: sigma + spine
        tanh_base_poly(10, c10);   // deg-9  in y: g gate
        for (int i = 0; i < 14; ++i) {
            AC.sig[i]   = (float)(2.0 * c14[i]);
            AC.spine[i] = (float)(4.0 * c14[i]);
        }
        for (int i = 0; i < 10; ++i) AC.gg[i] = (float)c10[i];
    }

    zero_kernel<<<NBINS / 256, 256, 0, stream>>>(gbins);
    len_kernel<<<Bn / 4, 256, 0, stream>>>(x, lengths, gbins);
    sort_kernel<<<1, 1024, 0, stream>>>(lengths, gbins, perm);
    lstm_kernel<<<Bn * 8 / 256, 256, 0, stream>>>(x, Wih, Whh, bih, bhh,
                                                  lengths, perm, out, AC);
}

// Round 7
// 653.609 us; speedup vs baseline: 1.1624x; 1.1624x over previous
//
#include <hip/hip_runtime.h>
#include <cmath>

// Problem constants (fixed by the reference).
#define Bn    16384
#define Tn    2048
#define HIDn  5
#define NBINS 2048

typedef float v2f __attribute__((ext_vector_type(2)));

static __device__ __forceinline__ float rcp_fast(float v) {
    return __builtin_amdgcn_rcpf(v);
}
static __device__ __forceinline__ float exp2_fast(float v) {
    return __builtin_amdgcn_exp2f(v);
}
static __device__ __forceinline__ float med3(float x, float lo, float hi) {
    return __builtin_amdgcn_fmed3f(x, lo, hi);   // 1-op clamp
}

// Broadcast lane (8g + K) to all lanes of each 8-lane group (ds_swizzle BitMode:
// new_src = (lane & 0x18) | K).
template <int K>
static __device__ __forceinline__ float bcast8(float v) {
    return __int_as_float(
        __builtin_amdgcn_ds_swizzle(__float_as_int(v), (K << 5) | 0x18));
}

// Spine tanh polynomial coefficients, host-computed (see kernel_launch):
// tanh(c) = cc * P(cc*cc) for cc = clamp(c,+-4), P(u) = G(u/16) with
// G(y) = tanh(4*sqrt(y))/(4*sqrt(y)) Chebyshev-interpolated on y in [0,1]
// (N=14, err ~2e-5) and the 16^-i domain scale folded exactly (ldexp).
// NAMED FIELDS ONLY — never index via pointer (R6: address-taken kernarg
// struct went to scratch and put ~300cy of loads on the chain).
struct SpineC {
    float p0, p1, p2, p3, p4, p5, p6;
    float p7, p8, p9, p10, p11, p12, p13;
};

// ---------------------------------------------------------------------------
// Pass 0: zero the global histogram bins (ws is poisoned 0xAA by the harness).
// ---------------------------------------------------------------------------
__global__ void zero_kernel(int* __restrict__ gbins) {
    gbins[blockIdx.x * 256 + threadIdx.x] = 0;
}

// ---------------------------------------------------------------------------
// Pass 1: lengths[b] = count of nonzero x[b,t] (exact reference mask.sum
// semantics) + histogram of descending-key d = NBINS - len.
// ---------------------------------------------------------------------------
__global__ __launch_bounds__(256) void len_kernel(const float* __restrict__ x,
                                                  int* __restrict__ lengths,
                                                  int* __restrict__ gbins) {
    const int gtid = blockIdx.x * 256 + threadIdx.x;
    const int row  = gtid >> 6;
    const int lane = threadIdx.x & 63;
    const float4* r = reinterpret_cast<const float4*>(x + (size_t)row * Tn);
    int cnt = 0;
    #pragma unroll
    for (int i = 0; i < Tn / 4 / 64; ++i) {
        float4 v = r[i * 64 + lane];
        cnt += (v.x != 0.0f) + (v.y != 0.0f) + (v.z != 0.0f) + (v.w != 0.0f);
    }
    #pragma unroll
    for (int off = 32; off > 0; off >>= 1) cnt += __shfl_xor(cnt, off, 64);
    if (lane == 0) {
        lengths[row] = cnt;
        const int d = max(0, min(NBINS - 1, NBINS - cnt));
        atomicAdd(&gbins[d], 1);
    }
}

// ---------------------------------------------------------------------------
// Pass 1.5: scan the histogram + scatter -> perm[] sorted by length DESC.
// ---------------------------------------------------------------------------
__global__ __launch_bounds__(1024) void sort_kernel(const int* __restrict__ lengths,
                                                    const int* __restrict__ gbins,
                                                    int* __restrict__ perm) {
    __shared__ int bins[NBINS];
    __shared__ int bsum[1024];
    const int tid = threadIdx.x;
    bins[tid]        = gbins[tid];
    bins[tid + 1024] = gbins[tid + 1024];
    __syncthreads();
    const int a0 = bins[2 * tid], a1 = bins[2 * tid + 1];
    const int s = a0 + a1;
    bsum[tid] = s;
    __syncthreads();
    int acc = s;
    for (int off = 1; off < 1024; off <<= 1) {
        int v = (tid >= off) ? bsum[tid - off] : 0;
        __syncthreads();
        acc += v;
        bsum[tid] = acc;
        __syncthreads();
    }
    const int excl = acc - s;
    bins[2 * tid]     = excl;
    bins[2 * tid + 1] = excl + a0;
    __syncthreads();
    for (int i = tid; i < Bn; i += 1024) {
        int d = NBINS - lengths[i];
        d = max(0, min(NBINS - 1, d));
        const int p = atomicAdd(&bins[d], 1);
        perm[p] = i;
    }
}

// ---------------------------------------------------------------------------
// Pass 2: LSTM. R5 structure (8 lanes/group, lane k=min(lsub,4) owns hidden k,
// ds_swizzle broadcast, 2 waves/SIMD, exp2 gates). Chain surgery this round
// (measured chain model: bcast 120 + ladder 40 + gates 128 + cn 8 + spine 136
// + commit 8 + hn 8 = 448):
//   - spine tanh via host-computed Chebyshev poly (named-scalar kernarg
//     struct -> SGPRs, no pointers): 136 -> ~64 on chain, +17 instrs issue
//   - tree ladder (R4-verified): 40 -> 24
//   - commit elimination: c,h updated unconditionally (past-len rows are
//     dead anyway); output stored IN-LOOP at tau == len-1 (predicated,
//     off-chain). Removes both cndmasks from the chain.
// New chain ~ 352; issue ~236 < chain, so still chain-bound.
// ---------------------------------------------------------------------------
__global__ __launch_bounds__(256, 2) void lstm_kernel(const float* __restrict__ x,
                                                      const float* __restrict__ Wih,
                                                      const float* __restrict__ Whh,
                                                      const float* __restrict__ bih,
                                                      const float* __restrict__ bhh,
                                                      const int* __restrict__ lengths,
                                                      const int* __restrict__ perm,
                                                      float* __restrict__ out,
                                                      SpineC SC) {
    const int gtid = blockIdx.x * 256 + threadIdx.x;
    const int grp  = gtid >> 3;              // group-of-8 index = sorted rank
    const int lsub = threadIdx.x & 7;
    const int k    = min(lsub, 4);           // owned hidden index

    // Symmetry-break: co-resident blocks on a CU get different priority.
    if ((blockIdx.x >> 8) & 1) __builtin_amdgcn_s_setprio(1);

    const int b     = perm[grp];
    const int len   = lengths[b];
    const int mstep = max(len, 1) - 1;       // step whose hn is the output

    // Gate rows: i=k, f=5+k, g=10+k, o=15+k. Pairs A=(i,f), B=(g,o).
    // Scale: i,f,o rows by -log2e (sigmoid via exp2), g row by -2*log2e
    // (tanh via 2*sigma(2g)-1). All folded into weights+bias.
    const float S1 = -1.4426950408889634f;   // -log2(e)
    const float S2 = 2.0f * S1;              // -2*log2(e)
    v2f wihA, wihB, bA, bB, whhA[HIDn], whhB[HIDn];
    {
        const int gi = k, gf = 5 + k, gg = 10 + k, go = 15 + k;
        wihA = (v2f){ Wih[gi] * S1, Wih[gf] * S1 };
        wihB = (v2f){ Wih[gg] * S2, Wih[go] * S1 };
        bA   = (v2f){ (bih[gi] + bhh[gi]) * S1, (bih[gf] + bhh[gf]) * S1 };
        bB   = (v2f){ (bih[gg] + bhh[gg]) * S2, (bih[go] + bhh[go]) * S1 };
        #pragma unroll
        for (int kk = 0; kk < HIDn; ++kk) {
            whhA[kk] = (v2f){ Whh[gi * HIDn + kk] * S1, Whh[gf * HIDn + kk] * S1 };
            whhB[kk] = (v2f){ Whh[gg * HIDn + kk] * S2, Whh[go * HIDn + kk] * S1 };
        }
    }

    const float* xrow = x + (size_t)b * Tn;
    float h0 = 0, h1 = 0, h2 = 0, h3 = 0, h4 = 0;
    float c = 0;

    float4 xq = *reinterpret_cast<const float4*>(xrow);
    for (int t = 0; __any(t < len); t += 4) {
        const float4 xn = *reinterpret_cast<const float4*>(xrow + min(t + 4, Tn - 4));
        const float xs[4] = { xq.x, xq.y, xq.z, xq.w };
        #pragma unroll
        for (int s = 0; s < 4; ++s) {
            const float xv = xs[s];
            // Pre-activations: x-part off-chain, depth-3 tree over h0..h4.
            const v2f xA = xv * wihA + bA;
            const v2f xB = xv * wihB + bB;
            const v2f tA0 = h0 * whhA[0] + xA;
            const v2f tB0 = h0 * whhB[0] + xB;
            const v2f mA2 = h2 * whhA[2];
            const v2f mB2 = h2 * whhB[2];
            const v2f tA1 = h1 * whhA[1] + mA2;
            const v2f tB1 = h1 * whhB[1] + mB2;
            const v2f mA4 = h4 * whhA[4];
            const v2f mB4 = h4 * whhB[4];
            const v2f tA2 = h3 * whhA[3] + mA4;
            const v2f tB2 = h3 * whhB[3] + mB4;
            const v2f pA = (tA0 + tA1) + tA2;
            const v2f pB = (tB0 + tB1) + tB2;

            // Exact gate activations via hardware exp2 (args carry -log2e).
            const float eI = exp2_fast(pA.x);
            const float eF = exp2_fast(pA.y);
            const float eG = exp2_fast(pB.x);
            const float eO = exp2_fast(pB.y);
            const float gi_ = rcp_fast(1.0f + eI);   // sigmoid(i)
            const float gf_ = rcp_fast(1.0f + eF);   // sigmoid(f)
            const float rg  = rcp_fast(1.0f + eG);   // sigma(2g)
            const float oo  = rcp_fast(1.0f + eO);   // sigmoid(o)
            const float tg  = fmaf(2.0f, rg, -1.0f); // tanh(g)

            const float cn = fmaf(gf_, c, gi_ * tg);

            // Spine tanh(cn) via Chebyshev poly (depth-5 Estrin, no trans).
            const float cc = med3(cn, -4.0f, 4.0f);
            const float u  = cc * cc;
            const float A0 = fmaf(u, SC.p1,  SC.p0);
            const float A1 = fmaf(u, SC.p3,  SC.p2);
            const float A2 = fmaf(u, SC.p5,  SC.p4);
            const float A3 = fmaf(u, SC.p7,  SC.p6);
            const float A4 = fmaf(u, SC.p9,  SC.p8);
            const float A5 = fmaf(u, SC.p11, SC.p10);
            const float A6 = fmaf(u, SC.p13, SC.p12);
            const float u2 = u * u, u4 = u2 * u2, u8 = u4 * u4;
            const float B0 = fmaf(u2, A1, A0);
            const float B1 = fmaf(u2, A3, A2);
            const float B2 = fmaf(u2, A5, A4);
            const float D0 = fmaf(u4, B1, B0);
            const float D1 = fmaf(u4, A6, B2);
            const float Pc = fmaf(u8, D1, D0);
            const float hn = (cc * Pc) * oo;

            // Output store at tau == len-1 (predicated, off-chain). State
            // updates are UNCONDITIONAL: rows past len are dead, their
            // evolving c/h are never read.
            if (lsub < HIDn && (t + s) == mstep)
                out[(size_t)b * HIDn + lsub] = hn;
            c = cn;

            h0 = bcast8<0>(hn);
            h1 = bcast8<1>(hn);
            h2 = bcast8<2>(hn);
            h3 = bcast8<3>(hn);
            h4 = bcast8<4>(hn);
        }
        xq = xn;
    }
}

// ---------------------------------------------------------------------------
// Host: Chebyshev interpolation of G(y) = tanh(4*sqrt(y))/(4*sqrt(y)) on
// y in [0,1] (Newton divided differences at Chebyshev nodes, double precision,
// expanded to monomials). Verified correct in round 6 (passed, absmax 3.9e-3).
// ---------------------------------------------------------------------------
static void tanh_base_poly(int N, double* c) {
    double yj[16], fj[16];
    for (int j = 0; j < N; ++j) {
        const double v = cos(M_PI * (2 * j + 1) / (2.0 * N));
        const double y = 0.5 + 0.5 * v;
        const double xx = 4.0 * sqrt(y);
        yj[j] = y;
        fj[j] = tanh(xx) / xx;
    }
    for (int k = 1; k < N; ++k)
        for (int j = N - 1; j >= k; --j)
            fj[j] = (fj[j] - fj[j - 1]) / (yj[j] - yj[j - k]);
    for (int i = 0; i < 16; ++i) c[i] = 0.0;
    c[0] = fj[N - 1];
    int deg = 0;
    for (int j = N - 2; j >= 0; --j) {
        for (int i = deg; i >= 0; --i) {
            c[i + 1] += c[i];
            c[i] = -yj[j] * c[i];
        }
        ++deg;
        c[0] += fj[j];
    }
}

extern "C" void kernel_launch(void* const* d_in, const int* in_sizes, int n_in,
                              void* d_out, int out_size, void* d_ws, size_t ws_size,
                              hipStream_t stream) {
    const float* x   = (const float*)d_in[0];  // [B,1,T,1]
    const float* Wih = (const float*)d_in[1];  // [20,1]
    const float* Whh = (const float*)d_in[2];  // [20,5]
    const float* bih = (const float*)d_in[3];  // [20]
    const float* bhh = (const float*)d_in[4];  // [20]
    float* out = (float*)d_out;                // [1,B,5]

    int* lengths = (int*)d_ws;                 // [0, Bn)
    int* perm    = lengths + Bn;               // [Bn, 2Bn)
    int* gbins   = perm + Bn;                  // [2Bn, 2Bn+NBINS)

    // Host-side spine coefficients: P(u) = G(u/16), 16^-i folded exactly.
    SpineC SC;
    {
        double c14[16];
        tanh_base_poly(14, c14);
        float p[14];
        for (int i = 0; i < 14; ++i) p[i] = (float)ldexp(c14[i], -4 * i);
        SC.p0  = p[0];  SC.p1  = p[1];  SC.p2  = p[2];  SC.p3  = p[3];
        SC.p4  = p[4];  SC.p5  = p[5];  SC.p6  = p[6];  SC.p7  = p[7];
        SC.p8  = p[8];  SC.p9  = p[9];  SC.p10 = p[10]; SC.p11 = p[11];
        SC.p12 = p[12]; SC.p13 = p[13];
    }

    zero_kernel<<<NBINS / 256, 256, 0, stream>>>(gbins);
    len_kernel<<<Bn / 4, 256, 0, stream>>>(x, lengths, gbins);
    sort_kernel<<<1, 1024, 0, stream>>>(lengths, gbins, perm);
    lstm_kernel<<<Bn * 8 / 256, 256, 0, stream>>>(x, Wih, Whh, bih, bhh,
                                                  lengths, perm, out, SC);
}